// Round 7
// baseline (4536.166 us; speedup 1.0000x reference)
//
#include <hip/hip_runtime.h>
#include <cstdint>
#include <cstddef>

// Problem constants (AugmentedLstm: B=64, T=512, D=512, H=512)
#define BB 64
#define TT 512
#define DD 512
#define HH 512
#define SIXH 3072
#define NWG 32           // persistent recurrence workgroups (j-slices of 16)

typedef __attribute__((ext_vector_type(8))) short bf16x8;
typedef __attribute__((ext_vector_type(4))) float f32x4;
typedef __attribute__((ext_vector_type(4))) unsigned short u16x4;
typedef __attribute__((ext_vector_type(4))) int i32x4;

// ---- ws layout (byte offsets) ---------------------------------------------
#define WS_FLAGS 0u        // 2 ints: [0] fp32-inputs flag, [1] int64-lengths flag
#define WS_CNT   256u      // 128 per-wave step flags, stride 32 ints = 16384 B
#define WS_H     16640u    // 2 x [BB][HH] ushort bf16 h ping-pong (131072 B)
#define WS_C     147712u   // [BB][HH] float c (131072 B)
#define WS_PROJ  278784u   // proj chunk: [b][tl][6H] bf16, Tc*BB rows

// Coherent (L2-bypassing, L3-visible) 16B load / 8B store via explicit sc0 sc1.
#define CLOAD16(dst, ptr) \
    asm volatile("global_load_dwordx4 %0, %1, off sc0 sc1" : "=v"(dst) : "v"(ptr))
#define CSTORE8(ptr, val) \
    asm volatile("global_store_dwordx2 %0, %1, off sc0 sc1" :: "v"(ptr), "v"(val))
// normal-path 8B load, order-pinned relative to other volatile asm
#define NLOAD8(dst, ptr) \
    asm volatile("global_load_dwordx2 %0, %1, off" : "=v"(dst) : "v"(ptr))
// waitcnt tied to the 4 regs of one ki-chunk so MFMAs can't be hoisted above it
#define WAIT4(N, a,b,c,d) \
    asm volatile("s_waitcnt vmcnt(" N ")" : "+v"(a),"+v"(b),"+v"(c),"+v"(d))

__device__ __forceinline__ float bf2f(unsigned short u) {
    union { unsigned int i; float f; } v; v.i = ((unsigned int)u) << 16; return v.f;
}
__device__ __forceinline__ unsigned short f2bf(float f) {
    union { unsigned int i; float f; } v; v.f = f;
    unsigned int r = v.i + 0x7FFFu + ((v.i >> 16) & 1u);  // RNE
    return (unsigned short)(r >> 16);
}
__device__ __forceinline__ float sigm(float x) { return 1.0f / (1.0f + __expf(-x)); }
__device__ __forceinline__ float tanh_fast(float x) {
    return 1.0f - 2.0f / (__expf(2.0f * x) + 1.0f);   // NaN-free, exact at +-inf
}

__device__ __forceinline__ bf16x8 cvt8(const float* p) {
    bf16x8 o;
#pragma unroll
    for (int i = 0; i < 8; i++) o[i] = (short)f2bf(p[i]);
    return o;
}

// ---------------------------------------------------------------------------
// Detect input dtypes from raw bits (logic proven rounds 2-6).
// ---------------------------------------------------------------------------
__global__ void detect_kernel(const unsigned short* __restrict__ x16,
                              const int* __restrict__ len32,
                              int* __restrict__ flags) {
    const int lane = threadIdx.x;   // 64
    int bad = 0;
    for (int i = lane; i < 256; i += 64)
        if (fabsf(bf2f(x16[i])) > 1e4f) bad++;
#pragma unroll
    for (int off = 32; off; off >>= 1) bad += __shfl_down(bad, off);
    if (lane == 0) {
        flags[0] = (bad >= 16) ? 1 : 0;
        flags[1] = (len32[1] == 0 && len32[3] == 0 && len32[5] == 0) ? 1 : 0;
    }
}

// ---------------------------------------------------------------------------
// Proj chunk GEMM v2: block tile 128(M) x 64(N), 4 waves each 32x64 (2x4
// MFMA -> 8 MFMA per 6 wave-loads). projc[(b*Tc+tl)*6H + n] = x.w_in^T + b_in
// ---------------------------------------------------------------------------
template<int FP32>
__device__ __forceinline__ void proj_core(const void* __restrict__ xv,
                                          const void* __restrict__ wv,
                                          const void* __restrict__ bv,
                                          unsigned short* __restrict__ projc,
                                          int t0, int tc_shift) {
    const int tid  = threadIdx.x;
    const int wave = tid >> 6;
    const int lane = tid & 63;
    const int q    = lane >> 4;
    const int r    = lane & 15;

    const int m_blk  = blockIdx.y * 128 + wave * 32;
    const int n_base = blockIdx.x * 64;
    const int Tc     = 1 << tc_shift;
    const int b      = m_blk >> tc_shift;
    const int tl     = m_blk & (Tc - 1);

    const size_t xrow0 = (size_t)(b * TT + t0 + tl + r) * DD;
    const size_t xrow1 = (size_t)(b * TT + t0 + tl + 16 + r) * DD;
    size_t wrow[4];
#pragma unroll
    for (int ni = 0; ni < 4; ni++) wrow[ni] = (size_t)(n_base + ni * 16 + r) * DD;

    f32x4 acc[2][4] = {};
    const int koff = q * 8;
#pragma unroll 2
    for (int k0 = 0; k0 < DD; k0 += 32) {
        const int k = k0 + koff;
        bf16x8 a0, a1, bw[4];
        if (FP32) {
            const float* xf = (const float*)xv;
            const float* wf = (const float*)wv;
            a0 = cvt8(xf + xrow0 + k);  a1 = cvt8(xf + xrow1 + k);
#pragma unroll
            for (int ni = 0; ni < 4; ni++) bw[ni] = cvt8(wf + wrow[ni] + k);
        } else {
            const unsigned short* xb = (const unsigned short*)xv;
            const unsigned short* wb = (const unsigned short*)wv;
            a0 = *(const bf16x8*)(xb + xrow0 + k);  a1 = *(const bf16x8*)(xb + xrow1 + k);
#pragma unroll
            for (int ni = 0; ni < 4; ni++) bw[ni] = *(const bf16x8*)(wb + wrow[ni] + k);
        }
#pragma unroll
        for (int ni = 0; ni < 4; ni++) {
            acc[0][ni] = __builtin_amdgcn_mfma_f32_16x16x32_bf16(a0, bw[ni], acc[0][ni], 0, 0, 0);
            acc[1][ni] = __builtin_amdgcn_mfma_f32_16x16x32_bf16(a1, bw[ni], acc[1][ni], 0, 0, 0);
        }
    }

#pragma unroll
    for (int mi = 0; mi < 2; mi++) {
#pragma unroll
        for (int ni = 0; ni < 4; ni++) {
            const int n = n_base + ni * 16 + r;
            const float bias = FP32 ? ((const float*)bv)[n] : bf2f(((const unsigned short*)bv)[n]);
#pragma unroll
            for (int rr = 0; rr < 4; rr++) {
                const int m = m_blk + mi * 16 + q * 4 + rr;
                projc[(size_t)m * SIXH + n] = f2bf(acc[mi][ni][rr] + bias);
            }
        }
    }
}

__global__ __launch_bounds__(256) void proj_kernel(const void* xv, const void* wv, const void* bv,
                                                   unsigned short* projc, const int* flags,
                                                   int t0, int tc_shift) {
    if (flags[0]) proj_core<1>(xv, wv, bv, projc, t0, tc_shift);
    else          proj_core<0>(xv, wv, bv, projc, t0, tc_shift);
}

// ---------------------------------------------------------------------------
// Persistent recurrence kernel v5. Grid: NWG=32 x 256 threads (4 waves).
// Wave w owns batches [w*16, w*16+16); block owns j in [wg*16, wg*16+16).
// vs v4: (a) W_state A-fragments live in REGISTERS (80 x bf16x8 per wave,
// loaded once) -> zero LDS traffic in the loop, no __shared__ at all;
// (b) per-WAVE flags (128), each stored after that wave's own vmcnt(0)
// drain; every wave polls all 128 -> completely barrier-free main loop;
// (c) next-step projc prefetch issued as order-pinned asm loads right after
// the h loads so it flies under the MFMA section.
// ---------------------------------------------------------------------------
__global__ __launch_bounds__(256, 1) void rec_kernel(
    const unsigned short* __restrict__ projc,
    const void* __restrict__ wsv, const void* __restrict__ bsv,
    const int* __restrict__ len32,
    unsigned short* __restrict__ hbuf, float* __restrict__ cbuf,
    int* __restrict__ wgflag, void* __restrict__ outv,
    const int* __restrict__ flags, int t0, int Tc)
{
    const int fp32 = flags[0], i64 = flags[1];
    const int tid  = threadIdx.x;
    const int wv   = tid >> 6;    // wave = batch group (0..3)
    const int lane = tid & 63;
    const int q    = lane >> 4;
    const int r    = lane & 15;
    const int j0   = blockIdx.x * 16;
    const int b    = wv * 16 + r;              // this lane's batch
    const int fid  = blockIdx.x * 4 + wv;      // per-wave flag id (0..127)

    // --- W_state A-fragments in registers: wfrag[g*16+ki] ---
    // A-frag layout: lane holds A[j0 + (lane&15)][ki*32 + (lane>>4)*8 + j]
    bf16x8 wfrag[80];
    if (fp32) {
#pragma unroll
        for (int gk = 0; gk < 80; gk++) {
            const int g = gk >> 4, ki = gk & 15;
            wfrag[gk] = cvt8((const float*)wsv +
                             (size_t)(g * HH + j0 + r) * HH + ki * 32 + q * 8);
        }
    } else {
#pragma unroll
        for (int gk = 0; gk < 80; gk++) {
            const int g = gk >> 4, ki = gk & 15;
            wfrag[gk] = *(const bf16x8*)((const unsigned short*)wsv +
                             (size_t)(g * HH + j0 + r) * HH + ki * 32 + q * 8);
        }
    }

    // per-lane persistent state: lane owns batch b x (j = j0+q*4+jj)
    float bs[5][4];
#pragma unroll
    for (int g = 0; g < 5; g++)
#pragma unroll
        for (int jj = 0; jj < 4; jj++)
            bs[g][jj] = fp32 ? ((const float*)bsv)[g * HH + j0 + q * 4 + jj]
                             : bf2f(((const unsigned short*)bsv)[g * HH + j0 + q * 4 + jj]);

    const int len = i64 ? len32[2 * b] : len32[b];
    float creg[4];
#pragma unroll
    for (int jj = 0; jj < 4; jj++)
        creg[jj] = cbuf[b * HH + j0 + q * 4 + jj];

    union PU { unsigned long long u; u16x4 v; };
    unsigned long long pvc[6], pvn[6];
    {   // initial projc gate inputs for tl = 0
        const unsigned short* pb = projc + (size_t)b * Tc * SIXH + j0 + q * 4;
#pragma unroll
        for (int g = 0; g < 6; g++) pvc[g] = *(const unsigned long long*)(pb + g * HH);
    }

    // zero the vm counter so the in-loop WAIT4 counts are exact
    asm volatile("s_waitcnt vmcnt(0)" ::: "memory");

    union HU { i32x4 i; bf16x8 b; };
    union P8 { unsigned short s[4]; unsigned long long u; };

    for (int t = t0; t < t0 + Tc; t++) {
        const unsigned short* hcur = hbuf + (size_t)(t & 1) * (BB * HH);
        unsigned short*       hnxt = hbuf + (size_t)((t + 1) & 1) * (BB * HH);

        if (t > t0) {   // per-wave poll: all 128 producer-wave flags >= t
            bool done;
            do {
                int f0 = __hip_atomic_load(&wgflag[lane * 32], __ATOMIC_RELAXED,
                                           __HIP_MEMORY_SCOPE_AGENT);
                int f1 = __hip_atomic_load(&wgflag[(64 + lane) * 32], __ATOMIC_RELAXED,
                                           __HIP_MEMORY_SCOPE_AGENT);
                done = __all((f0 >= t) & (f1 >= t));
            } while (!done);
            asm volatile("" ::: "memory");
        }

        // --- issue all 16 coherent h loads (ki-major), then pv prefetch ---
        i32x4 hv[16];
#pragma unroll
        for (int ki = 0; ki < 16; ki++)
            CLOAD16(hv[ki], hcur + (size_t)b * HH + ki * 32 + q * 8);
        {
            const int tln = (t - t0 + 1 < Tc) ? (t - t0 + 1) : (Tc - 1);
            const unsigned short* pb = projc + ((size_t)b * Tc + tln) * SIXH + j0 + q * 4;
#pragma unroll
            for (int g = 0; g < 6; g++) NLOAD8(pvn[g], pb + g * HH);
        }

        // --- GEMM: 80 MFMA in 4 chunks; outstanding = 16 h + 6 pv ---
        f32x4 acc[5] = {};
#define MFMA_CHUNK(KLO)                                                          \
        _Pragma("unroll")                                                        \
        for (int ki = (KLO); ki < (KLO) + 4; ki++) {                             \
            HU u; u.i = hv[ki];                                                  \
            _Pragma("unroll")                                                    \
            for (int g = 0; g < 5; g++)                                          \
                acc[g] = __builtin_amdgcn_mfma_f32_16x16x32_bf16(                \
                             wfrag[g * 16 + ki], u.b, acc[g], 0, 0, 0);          \
        }
        WAIT4("18", hv[0],  hv[1],  hv[2],  hv[3]);   MFMA_CHUNK(0)
        WAIT4("14", hv[4],  hv[5],  hv[6],  hv[7]);   MFMA_CHUNK(4)
        WAIT4("10", hv[8],  hv[9],  hv[10], hv[11]);  MFMA_CHUNK(8)
        WAIT4("6",  hv[12], hv[13], hv[14], hv[15]);  MFMA_CHUNK(12)
#undef MFMA_CHUNK

        // --- epilogue: lane owns batch b x 4 consecutive j ---
        P8 hp;
        float ov4[4];
#pragma unroll
        for (int jj = 0; jj < 4; jj++) {
            PU p0; p0.u = pvc[0];  PU p1; p1.u = pvc[1];  PU p2; p2.u = pvc[2];
            PU p3; p3.u = pvc[3];  PU p4; p4.u = pvc[4];  PU p5; p5.u = pvc[5];
            const float i_g = sigm(bf2f(p0.v[jj]) + acc[0][jj] + bs[0][jj]);
            const float f_g = sigm(bf2f(p1.v[jj]) + acc[1][jj] + bs[1][jj]);
            const float g_t = tanh_fast(bf2f(p2.v[jj]) + acc[2][jj] + bs[2][jj]);
            const float o_g = sigm(bf2f(p3.v[jj]) + acc[3][jj] + bs[3][jj]);
            const float hw  = sigm(bf2f(p4.v[jj]) + acc[4][jj] + bs[4][jj]);

            float c_new = i_g * g_t + f_g * creg[jj];
            float ov = o_g * tanh_fast(c_new);
            ov = hw * ov + (1.0f - hw) * bf2f(p5.v[jj]);
            if (t >= len) { ov = 0.0f; c_new = 0.0f; }
            creg[jj] = c_new;
            ov4[jj] = ov;
            hp.s[jj] = f2bf(ov);
        }

        // h for next step: coherent 8B store; drain h-store (+pv) only
        CSTORE8((void*)(hnxt + (size_t)b * HH + j0 + q * 4), hp.u);
        asm volatile("s_waitcnt vmcnt(0)" ::: "memory");
        if (lane == 0)
            __hip_atomic_store(&wgflag[fid * 32], t + 1,
                               __ATOMIC_RELAXED, __HIP_MEMORY_SCOPE_AGENT);

        // --- off-critical-path: output store; rotate pv ---
        if (fp32) {
            float* op = (float*)outv + ((size_t)b * TT + t) * HH + j0 + q * 4;
            *(float4*)op = make_float4(ov4[0], ov4[1], ov4[2], ov4[3]);
        } else {
            unsigned short* op = (unsigned short*)outv + ((size_t)b * TT + t) * HH + j0 + q * 4;
            *(unsigned long long*)op = hp.u;
        }
#pragma unroll
        for (int g = 0; g < 6; g++) pvc[g] = pvn[g];
    }

    // persist c for chunked mode
#pragma unroll
    for (int jj = 0; jj < 4; jj++)
        cbuf[b * HH + j0 + q * 4 + jj] = creg[jj];
}

// ---------------------------------------------------------------------------
extern "C" void kernel_launch(void* const* d_in, const int* in_sizes, int n_in,
                              void* d_out, int out_size, void* d_ws, size_t ws_size,
                              hipStream_t stream) {
    const void* xv      = d_in[0];
    const int*  len     = (const int*)d_in[1];
    const void* w_in    = d_in[2];
    const void* b_in    = d_in[3];
    const void* w_state = d_in[4];
    const void* b_state = d_in[5];

    char* ws = (char*)d_ws;
    int* flags  = (int*)(ws + WS_FLAGS);
    int* wgflag = (int*)(ws + WS_CNT);
    unsigned short* hbuf = (unsigned short*)(ws + WS_H);
    float* cbuf = (float*)(ws + WS_C);
    unsigned short* projc = (unsigned short*)(ws + WS_PROJ);

    // Largest proj chunk (timesteps, power of 2, >= 64) fitting ws.
    int tc_shift = 9;
    while (tc_shift > 6 &&
           WS_PROJ + ((size_t)BB << tc_shift) * SIXH * 2 > ws_size) tc_shift--;
    const int Tc = 1 << tc_shift;

    detect_kernel<<<1, 64, 0, stream>>>((const unsigned short*)xv, len, flags);
    // zero wave flags + h ping-pong + c
    hipMemsetAsync(ws + WS_CNT, 0, WS_PROJ - WS_CNT, stream);

    for (int c = 0; c < TT / Tc; c++) {
        const int t0 = c * Tc;
        proj_kernel<<<dim3(SIXH / 64, (BB << tc_shift) >> 7), 256, 0, stream>>>(
            xv, w_in, b_in, projc, flags, t0, tc_shift);
        rec_kernel<<<NWG, 256, 0, stream>>>(projc, w_state, b_state, len,
                                            hbuf, cbuf, wgflag, d_out, flags, t0, Tc);
    }
}